// Round 16
// baseline (85.758 us; speedup 1.0000x reference)
//
#include <hip/hip_runtime.h>
#include <cmath>

// x,y: (16,3,512,512) f32. Fused separable-Gaussian SSIM, scalar mean output.
// R15 quad structure (40KB LDS, 4 blocks/CU) + two new levers:
//  - v_pk_fma_f32/v_pk_mul_f32 packed math in the v-conv (float2-native)
//  - XCD-aware block swizzle so neighboring bands share an XCD's L2
constexpr int IMG_H = 512;
constexpr int IMG_W = 512;
constexpr int PLANES = 48;
constexpr int R_OUT = 8;                 // output rows per block (2 quads)
constexpr int BANDS = IMG_H / R_OUT;     // 64
constexpr int PSTR = 512;                // field-row dwords; col c at dword c
constexpr int NSLOT = 64;                // global accumulator slots (64B apart)
constexpr int NBLK = PLANES * BANDS;     // 3072 (divisible by 8 XCDs)
constexpr long long TOTAL_PIX = (long long)PLANES * IMG_H * IMG_W;

struct GWin2 { float2 g[11]; };          // g[k] duplicated into both halves

// packed 2xf32 ops (VOP3P). float2 -> even-aligned VGPR pair via "v".
__device__ __forceinline__ float2 pk_fma(float2 a, float2 b, float2 c) {
    float2 d;
    asm("v_pk_fma_f32 %0, %1, %2, %3" : "=v"(d) : "v"(a), "v"(b), "v"(c));
    return d;
}
__device__ __forceinline__ float2 pk_mul(float2 a, float2 b) {
    float2 d;
    asm("v_pk_mul_f32 %0, %1, %2" : "=v"(d) : "v"(a), "v"(b));
    return d;
}

// XOR bank swizzle on within-field-row dword offset (bits 2..4 ^= bits 5..7).
__device__ __forceinline__ int swzd(int d) { return d ^ (((d >> 5) & 7) << 2); }
__device__ __forceinline__ int swzd4(int b) { return b ^ ((b >> 3) & 7); }

template<bool CHK>
__device__ __forceinline__ float2 ld2(const float* __restrict__ base, int gr, int c0) {
    if (CHK && (unsigned)gr >= (unsigned)IMG_H) return make_float2(0.f, 0.f);
    return *(const float2*)(base + (size_t)gr * IMG_W + c0);
}

// horizontal 11-tap conv + SSIM over one LDS row (5 fields), 8 cols per lane.
__device__ __forceinline__ float hpass8(const float* __restrict__ fr0,
                                        int l, const int (&pb)[6],
                                        const GWin2& win) {
    float m[5][8];
#pragma unroll
    for (int f = 0; f < 5; ++f) {
        const float* fr = fr0 + f * PSTR;
        float w24[24];
#pragma unroll
        for (int B = 0; B < 6; ++B) {
            const float4 v = *(const float4*)&fr[pb[B]];
            w24[4 * B + 0] = v.x;  w24[4 * B + 1] = v.y;
            w24[4 * B + 2] = v.z;  w24[4 * B + 3] = v.w;
        }
        if (l == 0)  { w24[3] = w24[4] = w24[5] = w24[6] = w24[7] = 0.f; }
        if (l == 63) { w24[16] = w24[17] = w24[18] = w24[19] = w24[20] = 0.f; }
#pragma unroll
        for (int j = 0; j < 8; ++j) {
            float s = 0.f;
#pragma unroll
            for (int k = 0; k < 11; ++k) s += win.g[k].x * w24[j + 3 + k];
            m[f][j] = s;
        }
    }
    float ls = 0.f;
#pragma unroll
    for (int u = 0; u < 8; ++u) {
        const float mx  = m[0][u], my  = m[1][u];
        const float mxx = m[2][u], myy = m[3][u], mxy = m[4][u];
        const float mu_x_sq = mx * mx;
        const float mu_y_sq = my * my;
        const float mu_xy   = mx * my;
        const float sig_x  = mxx - mu_x_sq;
        const float sig_y  = myy - mu_y_sq;
        const float sig_xy = mxy - mu_xy;
        const float C1 = 0.01f * 0.01f;
        const float C2 = 0.03f * 0.03f;
        const float n = (2.f * mu_xy + C1) * (2.f * sig_xy + C2);
        const float d = (mu_x_sq + mu_y_sq + C1) * (sig_x + sig_y + C2);
        ls += n * __builtin_amdgcn_rcpf(d + 1e-8f);   // ~1 ulp; mean-safe
    }
    return ls;
}

template<bool CHK>
__device__ __forceinline__ float quad_rounds(const float* __restrict__ xp,
                                             const float* __restrict__ yp,
                                             int r0, int c0, int tid,
                                             float* __restrict__ hb,   // [4][5][PSTR]
                                             const GWin2& win)
{
    const int pws = swzd(2 * tid);       // v-write physical dword (b64-contiguous)
    const int row = tid >> 6, l = tid & 63;
    int pb[6];
#pragma unroll
    for (int B = 0; B < 6; ++B) {        // hoisted h-read addresses (clamped)
        int blk = 2 * l - 2 + B;
        blk = blk < 0 ? 0 : (blk > 127 ? 127 : blk);
        pb[B] = 4 * swzd4(blk);
    }
    float lsum = 0.f;

#pragma unroll 1
    for (int q = 0; q < 2; ++q) {
        const int rq = r0 + 4 * q;

        // ---- vertical 11-tap conv of {x,y,xx,yy,xy}, packed f32 ----
        float2 acc[4][5];
#pragma unroll
        for (int j = 0; j < 4; ++j)
#pragma unroll
            for (int f = 0; f < 5; ++f) acc[j][f] = make_float2(0.f, 0.f);

#pragma unroll
        for (int k = 0; k < 14; ++k) {
            const float2 xv = ld2<CHK>(xp, rq - 5 + k, c0);
            const float2 yv = ld2<CHK>(yp, rq - 5 + k, c0);
            const float2 pxx = pk_mul(xv, xv);
            const float2 pyy = pk_mul(yv, yv);
            const float2 pxy = pk_mul(xv, yv);
#pragma unroll
            for (int j = 0; j < 4; ++j) {
                const int t = k - j;               // compile-time
                if (t >= 0 && t <= 10) {
                    const float2 g = win.g[t];
                    acc[j][0] = pk_fma(g, xv,  acc[j][0]);
                    acc[j][1] = pk_fma(g, yv,  acc[j][1]);
                    acc[j][2] = pk_fma(g, pxx, acc[j][2]);
                    acc[j][3] = pk_fma(g, pyy, acc[j][3]);
                    acc[j][4] = pk_fma(g, pxy, acc[j][4]);
                }
            }
        }

#pragma unroll
        for (int j = 0; j < 4; ++j)
#pragma unroll
            for (int f = 0; f < 5; ++f)
                *(float2*)&hb[(j * 5 + f) * PSTR + pws] = acc[j][f];

        __syncthreads();

        lsum += hpass8(hb + row * 5 * PSTR, l, pb, win);

        __syncthreads();   // protect hbuf before next quad's writes
    }
    return lsum;
}

__global__ __launch_bounds__(256)
void ssim_pk_kernel(const float* __restrict__ x,
                    const float* __restrict__ y,
                    double* __restrict__ accum,
                    GWin2 win)
{
    __shared__ __align__(16) float hbuf[4 * 5 * PSTR];   // exactly 40960 B

    const int tid = threadIdx.x;
    // XCD-aware swizzle: physical blocks P=0,8,16,... land on XCD0 and get
    // consecutive LOGICAL ids -> neighboring bands share that XCD's L2.
    const int bid = blockIdx.x;
    const int L   = (bid & 7) * (NBLK / 8) + (bid >> 3);
    const int band  = L & (BANDS - 1);
    const int plane = L >> 6;
    const int r0    = band * R_OUT;
    const int c0    = tid * 2;

    const float* __restrict__ xp = x + (size_t)plane * (IMG_H * IMG_W);
    const float* __restrict__ yp = y + (size_t)plane * (IMG_H * IMG_W);

    float lsum;
    if (band >= 1 && band <= BANDS - 2)
        lsum = quad_rounds<false>(xp, yp, r0, c0, tid, hbuf, win);
    else
        lsum = quad_rounds<true>(xp, yp, r0, c0, tid, hbuf, win);

    // wave reduction, then one scattered global atomic per wave (no LDS)
#pragma unroll
    for (int off = 32; off; off >>= 1) lsum += __shfl_down(lsum, off);
    if ((tid & 63) == 0) {
        const int wid = L * 4 + (tid >> 6);
        atomicAdd(&accum[(wid & (NSLOT - 1)) * 8], (double)lsum);  // 64B stride
    }
}

__global__ void ssim_finalize_kernel(const double* __restrict__ accum,
                                     float* __restrict__ out)
{
    double s = 0.0;
    for (int i = 0; i < NSLOT; ++i) s += accum[i * 8];
    out[0] = (float)(s / (double)TOTAL_PIX);
}

extern "C" void kernel_launch(void* const* d_in, const int* in_sizes, int n_in,
                              void* d_out, int out_size, void* d_ws, size_t ws_size,
                              hipStream_t stream) {
    const float* x = (const float*)d_in[0];
    const float* y = (const float*)d_in[1];
    float* out = (float*)d_out;
    double* accum = (double*)d_ws;

    GWin2 win;
    {
        double g[11], s = 0.0;
        for (int i = 0; i < 11; ++i) {
            double d = (double)i - 5.0;
            g[i] = std::exp(-(d * d) / (2.0 * 1.5 * 1.5));
            s += g[i];
        }
        for (int i = 0; i < 11; ++i) {
            const float gf = (float)(g[i] / s);
            win.g[i] = make_float2(gf, gf);
        }
    }

    (void)hipMemsetAsync(d_ws, 0, NSLOT * 8 * sizeof(double), stream);

    ssim_pk_kernel<<<NBLK, 256, 0, stream>>>(x, y, accum, win);
    ssim_finalize_kernel<<<1, 1, 0, stream>>>(accum, out);
}

// Round 17
// 69.431 us; speedup vs baseline: 1.2352x; 1.2352x over previous
//
#include <hip/hip_runtime.h>
#include <cmath>

// x,y: (16,3,512,512) f32. Fused separable-Gaussian SSIM, scalar mean output.
// Combined best-of: 40KB LDS (4 blocks/CU, R15) + cross-quad row sharing in
// registers with prefetch under the h-pass (R10) + XCD-aware block swizzle
// (R16, FETCH 157->49MB). Scalar float2 math (pk-f32 proved rate-neutral).
constexpr int IMG_H = 512;
constexpr int IMG_W = 512;
constexpr int PLANES = 48;
constexpr int R_OUT = 8;                 // output rows per block (2 quads)
constexpr int BANDS = IMG_H / R_OUT;     // 64
constexpr int PSTR = 512;                // field-row dwords; col c at dword c
constexpr int NSLOT = 64;                // global accumulator slots (64B apart)
constexpr int NBLK = PLANES * BANDS;     // 3072 (divisible by 8 XCDs)
constexpr long long TOTAL_PIX = (long long)PLANES * IMG_H * IMG_W;

struct GWin { float g[11]; };

// XOR bank swizzle on within-field-row dword offset (bits 2..4 ^= bits 5..7).
__device__ __forceinline__ int swzd(int d) { return d ^ (((d >> 5) & 7) << 2); }
__device__ __forceinline__ int swzd4(int b) { return b ^ ((b >> 3) & 7); }

template<bool CHK>
__device__ __forceinline__ float2 ld2(const float* __restrict__ base, int gr, int c0) {
    if (CHK && (unsigned)gr >= (unsigned)IMG_H) return make_float2(0.f, 0.f);
    return *(const float2*)(base + (size_t)gr * IMG_W + c0);
}

// horizontal 11-tap conv + SSIM over one LDS row (5 fields), 8 cols per lane.
__device__ __forceinline__ float hpass8(const float* __restrict__ fr0,
                                        int l, const int (&pb)[6],
                                        const GWin& win) {
    float m[5][8];
#pragma unroll
    for (int f = 0; f < 5; ++f) {
        const float* fr = fr0 + f * PSTR;
        float w24[24];
#pragma unroll
        for (int B = 0; B < 6; ++B) {
            const float4 v = *(const float4*)&fr[pb[B]];
            w24[4 * B + 0] = v.x;  w24[4 * B + 1] = v.y;
            w24[4 * B + 2] = v.z;  w24[4 * B + 3] = v.w;
        }
        if (l == 0)  { w24[3] = w24[4] = w24[5] = w24[6] = w24[7] = 0.f; }
        if (l == 63) { w24[16] = w24[17] = w24[18] = w24[19] = w24[20] = 0.f; }
        // output col c = 8l+j: window cols c-5..c+5 -> w24[j+3+k]
#pragma unroll
        for (int j = 0; j < 8; ++j) {
            float s = 0.f;
#pragma unroll
            for (int k = 0; k < 11; ++k) s += win.g[k] * w24[j + 3 + k];
            m[f][j] = s;
        }
    }
    float ls = 0.f;
#pragma unroll
    for (int u = 0; u < 8; ++u) {
        const float mx  = m[0][u], my  = m[1][u];
        const float mxx = m[2][u], myy = m[3][u], mxy = m[4][u];
        const float mu_x_sq = mx * mx;
        const float mu_y_sq = my * my;
        const float mu_xy   = mx * my;
        const float sig_x  = mxx - mu_x_sq;
        const float sig_y  = myy - mu_y_sq;
        const float sig_xy = mxy - mu_xy;
        const float C1 = 0.01f * 0.01f;
        const float C2 = 0.03f * 0.03f;
        const float n = (2.f * mu_xy + C1) * (2.f * sig_xy + C2);
        const float d = (mu_x_sq + mu_y_sq + C1) * (sig_x + sig_y + C2);
        ls += n * __builtin_amdgcn_rcpf(d + 1e-8f);   // ~1 ulp; mean-safe
    }
    return ls;
}

// v-conv of 4 rows from 14 resident register rows; write to swizzled LDS
template<int I0>
__device__ __forceinline__ void vconv4(const float2 (&xr)[18], const float2 (&yr)[18],
                                       float* __restrict__ hb, int pws,
                                       const GWin& win) {
    float2 acc[4][5];
#pragma unroll
    for (int j = 0; j < 4; ++j)
#pragma unroll
        for (int f = 0; f < 5; ++f) acc[j][f] = make_float2(0.f, 0.f);
#pragma unroll
    for (int k = 0; k < 14; ++k) {
        const float2 xv = xr[I0 + k], yv = yr[I0 + k];
        const float2 pxx = make_float2(xv.x * xv.x, xv.y * xv.y);
        const float2 pyy = make_float2(yv.x * yv.x, yv.y * yv.y);
        const float2 pxy = make_float2(xv.x * yv.x, xv.y * yv.y);
#pragma unroll
        for (int j = 0; j < 4; ++j) {
            const int t = k - j;               // compile-time
            if (t >= 0 && t <= 10) {
                const float g = win.g[t];
                acc[j][0].x += g * xv.x;   acc[j][0].y += g * xv.y;
                acc[j][1].x += g * yv.x;   acc[j][1].y += g * yv.y;
                acc[j][2].x += g * pxx.x;  acc[j][2].y += g * pxx.y;
                acc[j][3].x += g * pyy.x;  acc[j][3].y += g * pyy.y;
                acc[j][4].x += g * pxy.x;  acc[j][4].y += g * pxy.y;
            }
        }
    }
#pragma unroll
    for (int j = 0; j < 4; ++j)
#pragma unroll
        for (int f = 0; f < 5; ++f)
            *(float2*)&hb[(j * 5 + f) * PSTR + pws] = acc[j][f];
}

template<bool CHK>
__device__ __forceinline__ float band_body(const float* __restrict__ xp,
                                           const float* __restrict__ yp,
                                           int r0, int c0, int tid,
                                           float* __restrict__ hb,
                                           const GWin& win)
{
    const int pws = swzd(2 * tid);
    const int row = tid >> 6, l = tid & 63;
    int pb[6];
#pragma unroll
    for (int B = 0; B < 6; ++B) {
        int blk = 2 * l - 2 + B;
        blk = blk < 0 ? 0 : (blk > 127 ? 127 : blk);
        pb[B] = 4 * swzd4(blk);
    }

    // rows i=0..17 <-> image rows r0-5+i. Load 0..13 now (quad 0).
    float2 xr[18], yr[18];
#pragma unroll
    for (int i = 0; i < 14; ++i) {
        xr[i] = ld2<CHK>(xp, r0 - 5 + i, c0);
        yr[i] = ld2<CHK>(yp, r0 - 5 + i, c0);
    }

    // quad 0: rows r0..r0+3 from xr[0..13]
    vconv4<0>(xr, yr, hb, pws, win);
    __syncthreads();

    // prefetch quad-1-only rows (i=14..17) under the q0 h-pass
#pragma unroll
    for (int i = 14; i < 18; ++i) {
        xr[i] = ld2<CHK>(xp, r0 - 5 + i, c0);
        yr[i] = ld2<CHK>(yp, r0 - 5 + i, c0);
    }

    float lsum = hpass8(hb + row * 5 * PSTR, l, pb, win);
    __syncthreads();                      // protect hbuf before q1 writes

    // quad 1: rows r0+4..r0+7 from xr[4..17]
    vconv4<4>(xr, yr, hb, pws, win);
    __syncthreads();

    lsum += hpass8(hb + row * 5 * PSTR, l, pb, win);
    return lsum;
}

__global__ __launch_bounds__(256)
void ssim_share_kernel(const float* __restrict__ x,
                       const float* __restrict__ y,
                       double* __restrict__ accum,
                       GWin win)
{
    __shared__ __align__(16) float hbuf[4 * 5 * PSTR];   // exactly 40960 B

    const int tid = threadIdx.x;
    // XCD-aware swizzle: consecutive logical bands share one XCD's L2.
    const int bid = blockIdx.x;
    const int L   = (bid & 7) * (NBLK / 8) + (bid >> 3);
    const int band  = L & (BANDS - 1);
    const int plane = L >> 6;
    const int r0    = band * R_OUT;
    const int c0    = tid * 2;

    const float* __restrict__ xp = x + (size_t)plane * (IMG_H * IMG_W);
    const float* __restrict__ yp = y + (size_t)plane * (IMG_H * IMG_W);

    float lsum;
    if (band >= 1 && band <= BANDS - 2)
        lsum = band_body<false>(xp, yp, r0, c0, tid, hbuf, win);
    else
        lsum = band_body<true>(xp, yp, r0, c0, tid, hbuf, win);

    // wave reduction, then one scattered global atomic per wave (no LDS)
#pragma unroll
    for (int off = 32; off; off >>= 1) lsum += __shfl_down(lsum, off);
    if ((tid & 63) == 0) {
        const int wid = L * 4 + (tid >> 6);
        atomicAdd(&accum[(wid & (NSLOT - 1)) * 8], (double)lsum);  // 64B stride
    }
}

__global__ void ssim_finalize_kernel(const double* __restrict__ accum,
                                     float* __restrict__ out)
{
    double s = 0.0;
    for (int i = 0; i < NSLOT; ++i) s += accum[i * 8];
    out[0] = (float)(s / (double)TOTAL_PIX);
}

extern "C" void kernel_launch(void* const* d_in, const int* in_sizes, int n_in,
                              void* d_out, int out_size, void* d_ws, size_t ws_size,
                              hipStream_t stream) {
    const float* x = (const float*)d_in[0];
    const float* y = (const float*)d_in[1];
    float* out = (float*)d_out;
    double* accum = (double*)d_ws;

    GWin win;
    {
        double g[11], s = 0.0;
        for (int i = 0; i < 11; ++i) {
            double d = (double)i - 5.0;
            g[i] = std::exp(-(d * d) / (2.0 * 1.5 * 1.5));
            s += g[i];
        }
        for (int i = 0; i < 11; ++i) win.g[i] = (float)(g[i] / s);
    }

    (void)hipMemsetAsync(d_ws, 0, NSLOT * 8 * sizeof(double), stream);

    ssim_share_kernel<<<NBLK, 256, 0, stream>>>(x, y, accum, win);
    ssim_finalize_kernel<<<1, 1, 0, stream>>>(accum, out);
}